// Round 3
// baseline (433.151 us; speedup 1.0000x reference)
//
#include <hip/hip_runtime.h>
#include <stdint.h>

// Fused RoPE: one block per sequence position s.
//  - Stage 1: threads 0..127 gather the block-diagonal cos/sin of
//    R[pos[s]] into LDS (cs[2k]=cos_k, cs[2k+1]=sin_k). Each needed
//    cache line of R is touched exactly once across the whole grid.
//  - Stage 2: all threads stream the bh = B*H rows of X that share this s.
//    Thread t's lane-within-row (d4 = t&31, a float4 = 2 rotation pairs)
//    is loop-invariant, so its cos/sin float4 is loaded from LDS once.
// No integer division anywhere; X/out accesses are fully coalesced float4.
__global__ __launch_bounds__(256) void rope_fused(
        const float* __restrict__ X,
        const float* __restrict__ R,
        const int* __restrict__ pos,
        float* __restrict__ out,
        int seq, int bh) {
    __shared__ float cs[128];

    const int s = blockIdx.x;
    const int t = threadIdx.x;

    const long p = (long)pos[s];
    const float* rp = R + p * 16384;   // R[p] : 128x128
    if (t < 64) {
        cs[2 * t] = rp[258 * t];                   // cos_k = R[p,2k,2k]
    } else if (t < 128) {
        int k = t - 64;
        cs[2 * k + 1] = rp[258 * k + 128];         // sin_k = R[p,2k+1,2k]
    }
    __syncthreads();

    const int d4 = t & 31;                         // float4 index within row
    const float4 c4 = *(const float4*)(cs + (d4 << 2));  // {c0,s0,c1,s1}

    const long rstride = (long)seq * 128;          // floats between rows (fixed s)
    const float* Xs = X + (long)s * 128 + (d4 << 2);
    float*       Os = out + (long)s * 128 + (d4 << 2);

    const int nvec = bh * 32;                      // float4 chunks this block owns
#pragma unroll 4
    for (int idx = t; idx < nvec; idx += 256) {
        const int row = idx >> 5;                  // which (b,h) row
        const long e = (long)row * rstride;
        float4 x = *(const float4*)(Xs + e);
        float4 o;
        o.x = c4.x * x.x - c4.y * x.y;
        o.y = c4.y * x.x + c4.x * x.y;
        o.z = c4.z * x.z - c4.w * x.w;
        o.w = c4.w * x.z + c4.z * x.w;
        *(float4*)(Os + e) = o;
    }
}

extern "C" void kernel_launch(void* const* d_in, const int* in_sizes, int n_in,
                              void* d_out, int out_size, void* d_ws, size_t ws_size,
                              hipStream_t stream) {
    const float* X   = (const float*)d_in[0];      // fp32 (B,H,S,128)
    const int*   pos = (const int*)d_in[1];        // int32 (S,)
    const float* R   = (const float*)d_in[2];      // fp32 (MAX_S,128,128)
    float* out       = (float*)d_out;

    const long n   = (long)in_sizes[0];            // B*H*S*128
    const int  seq = in_sizes[1];                  // S
    const int  bh  = (int)(n / ((long)seq * 128)); // B*H

    rope_fused<<<seq, 256, 0, stream>>>(X, R, pos, out, seq, bh);
}

// Round 4
// 423.132 us; speedup vs baseline: 1.0237x; 1.0237x over previous
//
#include <hip/hip_runtime.h>
#include <stdint.h>

// Kernel 1: compact the block-diagonal cos/sin of the gathered rotation
// matrices into tab[s*128 + 2k] = cos_k(pos[s]), tab[s*128+2k+1] = sin_k(pos[s]).
// ONE scattered load per thread (seq*128 threads) -> maximal memory-level
// parallelism on the latency-bound gather; ~full-chip thread residency puts
// all ~524K distinct cache-line touches in flight simultaneously.
// R layout (MAX_S,128,128) row-major:
//   cos_k = R[p, 2k,   2k] -> elem offset p*16384 + 258*k
//   sin_k = R[p, 2k+1, 2k] -> elem offset p*16384 + 258*k + 128
__global__ __launch_bounds__(256) void build_cs_table(
        const float* __restrict__ R,
        const int* __restrict__ pos,
        float* __restrict__ tab, int total) {      // total = seq*128
    int idx = blockIdx.x * blockDim.x + threadIdx.x;
    if (idx >= total) return;
    int s = idx >> 7;            // sequence index
    int j = idx & 127;           // 2k (+1 for sin)
    int k = j >> 1;
    int is_sin = j & 1;
    long p = (long)pos[s];
    tab[idx] = R[p * 16384 + 258 * k + (is_sin ? 128 : 0)];
}

// Kernel 2: linear streaming rotation. Thread i handles elements [4i,4i+4):
// perfectly sequential X read / out write across the whole tensor.
// s is recovered with a mask (seq is a power of two) -- no 64-bit math,
// no divide. Table reads hit L2 (2 MB, 64x reuse).
__global__ __launch_bounds__(256) void rope_apply_pow2(
        const float* __restrict__ X,
        const float* __restrict__ tab,
        float* __restrict__ out,
        int smask, int n4) {
    int i = blockIdx.x * blockDim.x + threadIdx.x;
    if (i >= n4) return;
    int s  = (i >> 5) & smask;                 // row = i>>5; s = row & (seq-1)
    int d0 = (i & 31) << 2;                    // float offset within d_k row

    float4 x  = *(const float4*)(X + ((long)i << 2));
    float4 cs = *(const float4*)(tab + s * 128 + d0);  // {c0,s0,c1,s1}
    float4 o;
    o.x = cs.x * x.x - cs.y * x.y;
    o.y = cs.y * x.x + cs.x * x.y;
    o.z = cs.z * x.z - cs.w * x.w;
    o.w = cs.w * x.z + cs.z * x.w;
    *(float4*)(out + ((long)i << 2)) = o;
}

// Generic-seq variant (32-bit modulo; row <= n4/32 fits int easily).
__global__ __launch_bounds__(256) void rope_apply_any(
        const float* __restrict__ X,
        const float* __restrict__ tab,
        float* __restrict__ out,
        int seq, int n4) {
    int i = blockIdx.x * blockDim.x + threadIdx.x;
    if (i >= n4) return;
    int s  = (i >> 5) % seq;
    int d0 = (i & 31) << 2;

    float4 x  = *(const float4*)(X + ((long)i << 2));
    float4 cs = *(const float4*)(tab + s * 128 + d0);
    float4 o;
    o.x = cs.x * x.x - cs.y * x.y;
    o.y = cs.y * x.x + cs.x * x.y;
    o.z = cs.z * x.z - cs.w * x.w;
    o.w = cs.w * x.z + cs.z * x.w;
    *(float4*)(out + ((long)i << 2)) = o;
}

extern "C" void kernel_launch(void* const* d_in, const int* in_sizes, int n_in,
                              void* d_out, int out_size, void* d_ws, size_t ws_size,
                              hipStream_t stream) {
    const float* X   = (const float*)d_in[0];      // fp32 (B,H,S,128)
    const int*   pos = (const int*)d_in[1];        // int32 (S,)
    const float* R   = (const float*)d_in[2];      // fp32 (MAX_S,128,128)
    float* out       = (float*)d_out;
    float* tab       = (float*)d_ws;               // seq*128 floats

    const int n   = in_sizes[0];                   // B*H*S*128 (fits int32)
    const int seq = in_sizes[1];                   // S
    const int n4  = n >> 2;

    const int blk = 256;
    const int total = seq * 128;
    build_cs_table<<<(total + blk - 1) / blk, blk, 0, stream>>>(R, pos, tab, total);

    if ((seq & (seq - 1)) == 0) {
        rope_apply_pow2<<<(n4 + blk - 1) / blk, blk, 0, stream>>>(
            X, tab, out, seq - 1, n4);
    } else {
        rope_apply_any<<<(n4 + blk - 1) / blk, blk, 0, stream>>>(
            X, tab, out, seq, n4);
    }
}